// Round 6
// baseline (5543.702 us; speedup 1.0000x reference)
//
#include <hip/hip_runtime.h>

// Problem constants (match reference)
constexpr int Bsz = 32;
constexpr int T   = 4096;
constexpr int P   = 64;
constexpr int IN  = 128;
constexpr int H   = 256;
constexpr long M  = (long)Bsz * T;   // 131072 rows
constexpr int FS  = 16;              // flag padding stride (ints, 64 B)
constexpr int C   = 8;               // pipeline chunk: rows per flag publish
constexpr int NC  = T / C;           // 512 chunks
constexpr int RW  = 320;             // padded 256-wide LDS row: 16 x (16+4)
constexpr int XW  = 192;             // padded 128-wide LDS row: 16 x (8+4)
constexpr int NPAIR = 16;            // 32 batches -> 16 pairs

// Progress flags (device-global; ws layout unchanged = 2*M*H floats).
// flag==v means "rows 0..v-1 of my output stream are globally visible".
// 4 producer roles (G,A,M,B) x 16 pairs.
__device__ int g_flags[4 * NPAIR * FS];

__global__ void zero_flags() {
  for (int i = threadIdx.x; i < 4 * NPAIR * FS; i += 256) g_flags[i] = 0;
}

// ---------------------------------------------------------------------------
// Cross-WG primitives (agent scope = coherent across per-XCD L2s).
// ---------------------------------------------------------------------------
__device__ __forceinline__ float gload(const float* p) {
  return __hip_atomic_load(const_cast<float*>(p), __ATOMIC_RELAXED,
                           __HIP_MEMORY_SCOPE_AGENT);
}
__device__ __forceinline__ void gstore(float* p, float v) {
  __hip_atomic_store(p, v, __ATOMIC_RELAXED, __HIP_MEMORY_SCOPE_AGENT);
}
__device__ __forceinline__ void wait_ge(const int* f, int target, int& seen) {
  if (seen >= target) return;
  int v = __hip_atomic_load(const_cast<int*>(f), __ATOMIC_ACQUIRE,
                            __HIP_MEMORY_SCOPE_AGENT);
  while (v < target) {
    __builtin_amdgcn_s_sleep(8);
    v = __hip_atomic_load(const_cast<int*>(f), __ATOMIC_ACQUIRE,
                          __HIP_MEMORY_SCOPE_AGENT);
  }
  seen = v;
}
__device__ __forceinline__ void publish(int* f, int v) {
  __hip_atomic_store(f, v, __ATOMIC_RELEASE, __HIP_MEMORY_SCOPE_AGENT);
}

// Light barrier: LDS visibility only (global ops ride across). Full barrier:
// drains vmcnt too (once per chunk, right before flag publish).
__device__ __forceinline__ void bar_lds() {
  asm volatile("s_waitcnt lgkmcnt(0)\n\ts_barrier" ::: "memory");
}
__device__ __forceinline__ void bar_full() {
  asm volatile("s_waitcnt vmcnt(0) lgkmcnt(0)\n\ts_barrier" ::: "memory");
}

__device__ __forceinline__ int padw(int c) { return (c >> 4) * 20 + (c & 15); }

// ds_swizzle pattern must be an integer-constant expression AT THE CALL SITE
// (R5 compile failure: runtime int param rejected) => template parameter.
template <int PAT>
__device__ __forceinline__ float swz(float x) {
  return __int_as_float(__builtin_amdgcn_ds_swizzle(__float_as_int(x), PAT));
}

// Butterfly over the 16 ks-lanes (lane = jg(bits0-1) x ks(bits2-5)); on
// return lanes 0..15 hold the full dot for j = wv*16 + jg*4 + jj2.
__device__ __forceinline__ float reduce16(const float acc[4], int bit4, int bit8) {
  float t0 = bit4 ? acc[0] : acc[2];
  float t1 = bit4 ? acc[1] : acc[3];
  float r0 = swz<0x101F>(t0), r1 = swz<0x101F>(t1);
  float u0 = (bit4 ? acc[2] : acc[0]) + r0;
  float u1 = (bit4 ? acc[3] : acc[1]) + r1;
  float t2 = bit8 ? u0 : u1;
  float r2 = swz<0x201F>(t2);
  float s  = (bit8 ? u1 : u0) + r2;
  s += swz<0x401F>(s);
  s += __shfl_xor(s, 32, 64);
  return s;
}

__device__ __forceinline__ float tanh_f(float x) {
  float e = __expf(2.f * x);
  return 1.f - 2.f * __builtin_amdgcn_rcpf(e + 1.f);
}

// ---------------------------------------------------------------------------
// Matvec: (4 j x 16 k) per thread against a 256-wide LDS vector (20-padded).
// ---------------------------------------------------------------------------
struct WTile { float4 w[4][4]; };

__device__ __forceinline__ void load_wtile(const float* Wm, int wv, int jg,
                                           int ks, WTile& wt) {
  const float4* W4 = (const float4*)Wm;
#pragma unroll
  for (int r = 0; r < 4; ++r)
#pragma unroll
    for (int q = 0; q < 4; ++q)
      wt.w[r][q] = W4[(long)(wv * 16 + jg * 4 + r) * (H / 4) + ks * 4 + q];
#pragma unroll
  for (int r = 0; r < 4; ++r)
#pragma unroll
    for (int q = 0; q < 4; ++q)
      asm volatile("" : "+v"(wt.w[r][q].x), "+v"(wt.w[r][q].y),
                        "+v"(wt.w[r][q].z), "+v"(wt.w[r][q].w));
}

__device__ __forceinline__ float matvec_reduce(const WTile& wt, const float* hb,
                                               int bit4, int bit8) {
  float4 h0 = *(const float4*)(hb + 0);
  float4 h1 = *(const float4*)(hb + 4);
  float4 h2 = *(const float4*)(hb + 8);
  float4 h3 = *(const float4*)(hb + 12);
  float acc[4] = {0.f, 0.f, 0.f, 0.f};
#pragma unroll
  for (int r = 0; r < 4; ++r) {
    acc[r] += wt.w[r][0].x * h0.x + wt.w[r][0].y * h0.y +
              wt.w[r][0].z * h0.z + wt.w[r][0].w * h0.w;
    acc[r] += wt.w[r][1].x * h1.x + wt.w[r][1].y * h1.y +
              wt.w[r][1].z * h1.z + wt.w[r][1].w * h1.w;
    acc[r] += wt.w[r][2].x * h2.x + wt.w[r][2].y * h2.y +
              wt.w[r][2].z * h2.z + wt.w[r][2].w * h2.w;
    acc[r] += wt.w[r][3].x * h3.x + wt.w[r][3].y * h3.y +
              wt.w[r][3].z * h3.z + wt.w[r][3].w * h3.w;
  }
  __builtin_amdgcn_sched_barrier(0);
  return reduce16(acc, bit4, bit8);
}

// ---------------------------------------------------------------------------
// Role G: pre1[t] = W_ih0 @ x[t] + b_ih0 + b_hh0, 2 batches/WG, streaming.
// x rows staged in LDS as 16 slices of 8 floats padded to 12 (16B-aligned,
// 2-way bank aliasing = free).
// ---------------------------------------------------------------------------
__device__ __forceinline__ void g_role(
    const float* __restrict__ xin, const float* __restrict__ Wih,
    const float* __restrict__ bi, const float* __restrict__ bh,
    float* pre1b, int* Gf, int pr, float* pool) {
  const int tid = threadIdx.x, lane = tid & 63, wv = tid >> 6;
  const int jg = lane & 3, ks = lane >> 2;
  const int bit4 = lane & 4, bit8 = lane & 8;
  const int jj2 = ((lane >> 1) & 2) | ((lane >> 3) & 1);

  const float4* W4 = (const float4*)Wih;
  float4 gwv[4][2];
#pragma unroll
  for (int r = 0; r < 4; ++r)
#pragma unroll
    for (int q = 0; q < 2; ++q)
      gwv[r][q] = W4[(long)(wv * 16 + jg * 4 + r) * (IN / 4) + ks * 2 + q];

  const int  jmine = wv * 16 + jg * 4 + jj2;
  const float bsum = bi[jmine] + bh[jmine];
  const long xb0 = (long)(2 * pr) * T * IN, xb1 = (long)(2 * pr + 1) * T * IN;
  float* o0 = pre1b + (long)(2 * pr) * T * H + jmine;
  float* o1 = pre1b + (long)(2 * pr + 1) * T * H + jmine;
  const int gr = tid >> 7, gc = tid & 127;         // 8 rows x 128 cols
  const int gcw = (gc >> 3) * 12 + (gc & 7);
  float* xrp = pool;                               // [bb][buf][C][XW]

  xrp[(0 * 2 + 0) * C * XW + gr * XW + gcw] = xin[xb0 + (long)gr * IN + gc];
  xrp[(1 * 2 + 0) * C * XW + gr * XW + gcw] = xin[xb1 + (long)gr * IN + gc];
  bar_lds();

#pragma unroll 1
  for (int k = 0; k < NC; ++k) {
    const int kn = k + 1;
    const bool more = (kn < NC);
    float n0 = 0.f, n1 = 0.f;
    if (more) {
      n0 = xin[xb0 + ((long)kn * C + gr) * IN + gc];
      n1 = xin[xb1 + ((long)kn * C + gr) * IN + gc];
    }
    const float* x0 = xrp + (0 * 2 + (k & 1)) * C * XW;
    const float* x1 = xrp + (1 * 2 + (k & 1)) * C * XW;
#pragma unroll 2
    for (int r = 0; r < C; ++r) {
      const int t = k * C + r;
      const float* xa = x0 + r * XW + ks * 12;
      float4 a0 = *(const float4*)(xa), a1 = *(const float4*)(xa + 4);
      float acc[4];
#pragma unroll
      for (int r2 = 0; r2 < 4; ++r2)
        acc[r2] = gwv[r2][0].x * a0.x + gwv[r2][0].y * a0.y +
                  gwv[r2][0].z * a0.z + gwv[r2][0].w * a0.w +
                  gwv[r2][1].x * a1.x + gwv[r2][1].y * a1.y +
                  gwv[r2][1].z * a1.z + gwv[r2][1].w * a1.w;
      float sA = reduce16(acc, bit4, bit8) + bsum;
      const float* xc = x1 + r * XW + ks * 12;
      float4 c0 = *(const float4*)(xc), c1 = *(const float4*)(xc + 4);
      float acd[4];
#pragma unroll
      for (int r2 = 0; r2 < 4; ++r2)
        acd[r2] = gwv[r2][0].x * c0.x + gwv[r2][0].y * c0.y +
                  gwv[r2][0].z * c0.z + gwv[r2][0].w * c0.w +
                  gwv[r2][1].x * c1.x + gwv[r2][1].y * c1.y +
                  gwv[r2][1].z * c1.z + gwv[r2][1].w * c1.w;
      float sB = reduce16(acd, bit4, bit8) + bsum;
      if (lane < 16) {
        gstore(o0 + (long)t * H, sA);
        gstore(o1 + (long)t * H, sB);
      }
    }
    if (more) {
      xrp[(0 * 2 + (kn & 1)) * C * XW + gr * XW + gcw] = n0;
      xrp[(1 * 2 + (kn & 1)) * C * XW + gr * XW + gcw] = n1;
    }
    bar_full();                       // drain pre1 gstores before publish
    if (tid == 0) publish(Gf, kn * C);
  }
}

// ---------------------------------------------------------------------------
// Role A/B: recurrent scan, 2 batches/WG sharing one W_hh register tile.
// Per step: 2x(matvec+butterfly+tanh) under ONE ds-latency window + ONE
// barrier; batch-1 FMA issue hides batch-0 butterfly latency.
// ---------------------------------------------------------------------------
__device__ __forceinline__ void scan_role2(
    const float* prebuf, const float* __restrict__ Wm, float* houtb,
    const int* inflag, int* outflag, int pr, float* pool) {
  const int tid = threadIdx.x, lane = tid & 63, wv = tid >> 6;
  const int jg = lane & 3, ks = lane >> 2;
  const int bit4 = lane & 4, bit8 = lane & 8;
  const int jj2 = ((lane >> 1) & 2) | ((lane >> 3) & 1);

  WTile wt; load_wtile(Wm, wv, jg, ks, wt);
  const int  jmine = wv * 16 + jg * 4 + jj2;
  const long base0 = (long)(2 * pr) * T * H;
  const long base1 = (long)(2 * pr + 1) * T * H;
  float* ho0 = houtb + base0 + jmine;
  float* ho1 = houtb + base1 + jmine;
  const int wr  = wv * 20 + (jg * 4 + jj2);
  const int prd = padw(jmine);
  const int sr0 = tid >> 8;                 // staging rows sr0, sr0+4
  const int sc  = padw(tid & 255);

  float* ringp = pool;                      // [bb][buf][C][RW]
  float* hdbp  = pool + 2 * 2 * C * RW;     // [bb][buf][RW]

  for (int i = tid; i < 4 * RW; i += 1024) hdbp[i] = 0.f;

  int seen = 0;
  wait_ge(inflag, C, seen);
  {
    float a0 = gload(prebuf + base0 + tid);
    float a1 = gload(prebuf + base0 + 1024 + tid);
    float c0 = gload(prebuf + base1 + tid);
    float c1 = gload(prebuf + base1 + 1024 + tid);
    ringp[(0 * 2 + 0) * C * RW + sr0 * RW + sc] = a0;
    ringp[(0 * 2 + 0) * C * RW + (sr0 + 4) * RW + sc] = a1;
    ringp[(1 * 2 + 0) * C * RW + sr0 * RW + sc] = c0;
    ringp[(1 * 2 + 0) * C * RW + (sr0 + 4) * RW + sc] = c1;
  }
  bar_full();

#pragma unroll 1
  for (int k = 0; k < NC; ++k) {
    const int kn = k + 1;
    const bool more = (kn < NC);
    float s00 = 0.f, s01 = 0.f, s10 = 0.f, s11 = 0.f;
    if (more) {
      wait_ge(inflag, (kn + 1) * C, seen);
      const float* n0 = prebuf + base0 + (long)kn * C * H;
      const float* n1 = prebuf + base1 + (long)kn * C * H;
      s00 = gload(n0 + tid); s01 = gload(n0 + 1024 + tid);
      s10 = gload(n1 + tid); s11 = gload(n1 + 1024 + tid);
    }
    const float* rb0 = ringp + (0 * 2 + (k & 1)) * C * RW;
    const float* rb1 = ringp + (1 * 2 + (k & 1)) * C * RW;
#pragma unroll 2
    for (int r = 0; r < C; ++r) {
      const int t = k * C + r;
      float p0 = rb0[r * RW + prd];
      float p1 = rb1[r * RW + prd];
      float sA = matvec_reduce(wt, hdbp + (0 * 2 + (r & 1)) * RW + ks * 20, bit4, bit8);
      float hn0 = tanh_f(p0 + sA);
      float sB = matvec_reduce(wt, hdbp + (1 * 2 + (r & 1)) * RW + ks * 20, bit4, bit8);
      float hn1 = tanh_f(p1 + sB);
      if (lane < 16) {
        hdbp[(0 * 2 + ((r + 1) & 1)) * RW + wr] = hn0;
        hdbp[(1 * 2 + ((r + 1) & 1)) * RW + wr] = hn1;
        gstore(ho0 + (long)t * H, hn0);
        gstore(ho1 + (long)t * H, hn1);
      }
      if (r != C - 1) bar_lds();
    }
    if (more) {
      float* w0 = ringp + (0 * 2 + (kn & 1)) * C * RW;
      float* w1 = ringp + (1 * 2 + (kn & 1)) * C * RW;
      w0[sr0 * RW + sc] = s00; w0[(sr0 + 4) * RW + sc] = s01;
      w1[sr0 * RW + sc] = s10; w1[(sr0 + 4) * RW + sc] = s11;
    }
    bar_full();                        // drain h gstores + ring ds_writes
    if (tid == 0) publish(outflag, kn * C);
  }
}

// ---------------------------------------------------------------------------
// Role M: pre2[t] = W_ih1 @ h1[t] + b_ih1 + b_hh1, 2 batches/WG, no per-step
// barrier (feed-forward).
// ---------------------------------------------------------------------------
__device__ __forceinline__ void mid_role2(
    const float* h1b, const float* __restrict__ Wm,
    const float* __restrict__ bi, const float* __restrict__ bh,
    float* pre2b, const int* Af, int* Mf, int pr, float* pool) {
  const int tid = threadIdx.x, lane = tid & 63, wv = tid >> 6;
  const int jg = lane & 3, ks = lane >> 2;
  const int bit4 = lane & 4, bit8 = lane & 8;
  const int jj2 = ((lane >> 1) & 2) | ((lane >> 3) & 1);

  WTile wt; load_wtile(Wm, wv, jg, ks, wt);
  const int  jmine = wv * 16 + jg * 4 + jj2;
  const float bsum = bi[jmine] + bh[jmine];
  const long base0 = (long)(2 * pr) * T * H;
  const long base1 = (long)(2 * pr + 1) * T * H;
  float* o0 = pre2b + base0 + jmine;
  float* o1 = pre2b + base1 + jmine;
  const int sr0 = tid >> 8;
  const int sc  = padw(tid & 255);
  float* ringp = pool;

  int seen = 0;
  wait_ge(Af, C, seen);
  {
    float a0 = gload(h1b + base0 + tid);
    float a1 = gload(h1b + base0 + 1024 + tid);
    float c0 = gload(h1b + base1 + tid);
    float c1 = gload(h1b + base1 + 1024 + tid);
    ringp[(0 * 2 + 0) * C * RW + sr0 * RW + sc] = a0;
    ringp[(0 * 2 + 0) * C * RW + (sr0 + 4) * RW + sc] = a1;
    ringp[(1 * 2 + 0) * C * RW + sr0 * RW + sc] = c0;
    ringp[(1 * 2 + 0) * C * RW + (sr0 + 4) * RW + sc] = c1;
  }
  bar_lds();

#pragma unroll 1
  for (int k = 0; k < NC; ++k) {
    const int kn = k + 1;
    const bool more = (kn < NC);
    float s00 = 0.f, s01 = 0.f, s10 = 0.f, s11 = 0.f;
    if (more) {
      wait_ge(Af, (kn + 1) * C, seen);
      const float* n0 = h1b + base0 + (long)kn * C * H;
      const float* n1 = h1b + base1 + (long)kn * C * H;
      s00 = gload(n0 + tid); s01 = gload(n0 + 1024 + tid);
      s10 = gload(n1 + tid); s11 = gload(n1 + 1024 + tid);
    }
    const float* rb0 = ringp + (0 * 2 + (k & 1)) * C * RW;
    const float* rb1 = ringp + (1 * 2 + (k & 1)) * C * RW;
#pragma unroll 2
    for (int r = 0; r < C; ++r) {
      const int t = k * C + r;
      float sA = matvec_reduce(wt, rb0 + r * RW + ks * 20, bit4, bit8) + bsum;
      float sB = matvec_reduce(wt, rb1 + r * RW + ks * 20, bit4, bit8) + bsum;
      if (lane < 16) {
        gstore(o0 + (long)t * H, sA);
        gstore(o1 + (long)t * H, sB);
      }
    }
    if (more) {
      float* w0 = ringp + (0 * 2 + (kn & 1)) * C * RW;
      float* w1 = ringp + (1 * 2 + (kn & 1)) * C * RW;
      w0[sr0 * RW + sc] = s00; w0[(sr0 + 4) * RW + sc] = s01;
      w1[sr0 * RW + sc] = s10; w1[(sr0 + 4) * RW + sc] = s11;
    }
    bar_full();                        // drain pre2 gstores before publish
    if (tid == 0) publish(Mf, kn * C);
  }
}

// ---------------------------------------------------------------------------
// Role F: out[t][p] = sigmoid(h2[t]·fcW[p] + fcb[p]), 2 batches/WG.
// ---------------------------------------------------------------------------
__device__ __forceinline__ void fc_role2(
    const float* h2b, const float* __restrict__ fcWm,
    const float* __restrict__ fcbv, float* __restrict__ outp,
    const int* Bf, int pr, float* pool) {
  const int tid = threadIdx.x, lane = tid & 63, wv = tid >> 6;
  const int jg = lane & 3, ks = lane >> 2;
  const int p = wv * 4 + jg;

  const float4* W4 = (const float4*)fcWm;
  float4 fw[4];
#pragma unroll
  for (int q = 0; q < 4; ++q) fw[q] = W4[(long)p * (H / 4) + ks * 4 + q];
  const float fb = fcbv[p];
  const long base0 = (long)(2 * pr) * T * H;
  const long base1 = (long)(2 * pr + 1) * T * H;
  const long ob0 = (long)(2 * pr) * T * P;
  const long ob1 = (long)(2 * pr + 1) * T * P;
  const int sr0 = tid >> 8;
  const int sc  = padw(tid & 255);
  float* ringp = pool;

  int seen = 0;
  wait_ge(Bf, C, seen);
  {
    float a0 = gload(h2b + base0 + tid);
    float a1 = gload(h2b + base0 + 1024 + tid);
    float c0 = gload(h2b + base1 + tid);
    float c1 = gload(h2b + base1 + 1024 + tid);
    ringp[(0 * 2 + 0) * C * RW + sr0 * RW + sc] = a0;
    ringp[(0 * 2 + 0) * C * RW + (sr0 + 4) * RW + sc] = a1;
    ringp[(1 * 2 + 0) * C * RW + sr0 * RW + sc] = c0;
    ringp[(1 * 2 + 0) * C * RW + (sr0 + 4) * RW + sc] = c1;
  }
  bar_lds();

#pragma unroll 1
  for (int k = 0; k < NC; ++k) {
    const int kn = k + 1;
    const bool more = (kn < NC);
    float s00 = 0.f, s01 = 0.f, s10 = 0.f, s11 = 0.f;
    if (more) {
      wait_ge(Bf, (kn + 1) * C, seen);
      const float* n0 = h2b + base0 + (long)kn * C * H;
      const float* n1 = h2b + base1 + (long)kn * C * H;
      s00 = gload(n0 + tid); s01 = gload(n0 + 1024 + tid);
      s10 = gload(n1 + tid); s11 = gload(n1 + 1024 + tid);
    }
    const float* rb0 = ringp + (0 * 2 + (k & 1)) * C * RW;
    const float* rb1 = ringp + (1 * 2 + (k & 1)) * C * RW;
#pragma unroll 2
    for (int r = 0; r < C; ++r) {
      const int t = k * C + r;
      const float* hb = rb0 + r * RW + ks * 20;
      float4 h0 = *(const float4*)(hb + 0);
      float4 h1 = *(const float4*)(hb + 4);
      float4 h2 = *(const float4*)(hb + 8);
      float4 h3 = *(const float4*)(hb + 12);
      float s = fw[0].x * h0.x + fw[0].y * h0.y + fw[0].z * h0.z + fw[0].w * h0.w
              + fw[1].x * h1.x + fw[1].y * h1.y + fw[1].z * h1.z + fw[1].w * h1.w
              + fw[2].x * h2.x + fw[2].y * h2.y + fw[2].z * h2.z + fw[2].w * h2.w
              + fw[3].x * h3.x + fw[3].y * h3.y + fw[3].z * h3.z + fw[3].w * h3.w;
      s += swz<0x101F>(s); s += swz<0x201F>(s); s += swz<0x401F>(s);
      s += __shfl_xor(s, 32, 64);
      float sig0 = __builtin_amdgcn_rcpf(1.f + __expf(-(s + fb)));

      const float* hc = rb1 + r * RW + ks * 20;
      float4 g0 = *(const float4*)(hc + 0);
      float4 g1 = *(const float4*)(hc + 4);
      float4 g2 = *(const float4*)(hc + 8);
      float4 g3 = *(const float4*)(hc + 12);
      float u = fw[0].x * g0.x + fw[0].y * g0.y + fw[0].z * g0.z + fw[0].w * g0.w
              + fw[1].x * g1.x + fw[1].y * g1.y + fw[1].z * g1.z + fw[1].w * g1.w
              + fw[2].x * g2.x + fw[2].y * g2.y + fw[2].z * g2.z + fw[2].w * g2.w
              + fw[3].x * g3.x + fw[3].y * g3.y + fw[3].z * g3.z + fw[3].w * g3.w;
      u += swz<0x101F>(u); u += swz<0x201F>(u); u += swz<0x401F>(u);
      u += __shfl_xor(u, 32, 64);
      float sig1 = __builtin_amdgcn_rcpf(1.f + __expf(-(u + fb)));

      if (lane < 4) {
        outp[ob0 + (long)t * P + wv * 4 + lane] = sig0;
        outp[ob1 + (long)t * P + wv * 4 + lane] = sig1;
      }
    }
    if (more) {
      float* w0 = ringp + (0 * 2 + (kn & 1)) * C * RW;
      float* w1 = ringp + (1 * 2 + (kn & 1)) * C * RW;
      w0[sr0 * RW + sc] = s00; w0[(sr0 + 4) * RW + sc] = s01;
      w1[sr0 * RW + sc] = s10; w1[(sr0 + 4) * RW + sc] = s11;
    }
    bar_lds();                          // ring visibility only (no publish)
  }
}

// ---------------------------------------------------------------------------
// 5-stage pipeline, 80 co-resident WGs (role = blk>>4, pair = blk&15):
//   G: input GEMM stream  x    -> pre1   (bufPre)
//   A: layer-1 scan       pre1 -> h1     (bufH)
//   M: W_ih1 stream       h1   -> pre2   (bufPre, in-place: A staged pre1
//                                         rows r+2C before M writes row r)
//   B: layer-2 scan       pre2 -> h2     (bufH, in-place behind M's staging)
//   F: fc+sigmoid stream  h2   -> out
// Acyclic waits, full-depth buffers, 80 WGs x 16 waves all resident.
// ---------------------------------------------------------------------------
__global__ __attribute__((amdgpu_flat_work_group_size(1024, 1024),
                          amdgpu_waves_per_eu(4, 4)))
void pipeline(const float* __restrict__ input, float* bufPre, float* bufH,
              const float* __restrict__ W_ih0, const float* __restrict__ b_ih0,
              const float* __restrict__ b_hh0, const float* __restrict__ W_hh0,
              const float* __restrict__ W_ih1, const float* __restrict__ b_ih1,
              const float* __restrict__ b_hh1, const float* __restrict__ W_hh1,
              const float* __restrict__ fcW, const float* __restrict__ fcb,
              float* __restrict__ outp) {
  __shared__ float pool[2 * 2 * C * RW + 2 * 2 * RW];   // 46080 B
  const int blk = blockIdx.x, role = blk >> 4, pr = blk & 15;
  int* Gf = g_flags + (0 * NPAIR + pr) * FS;
  int* Af = g_flags + (1 * NPAIR + pr) * FS;
  int* Mf = g_flags + (2 * NPAIR + pr) * FS;
  int* Bf = g_flags + (3 * NPAIR + pr) * FS;

  if (role == 0) {
    g_role(input, W_ih0, b_ih0, b_hh0, bufPre, Gf, pr, pool);
  } else if (role == 1) {
    scan_role2(bufPre, W_hh0, bufH, Gf, Af, pr, pool);
  } else if (role == 2) {
    mid_role2(bufH, W_ih1, b_ih1, b_hh1, bufPre, Af, Mf, pr, pool);
  } else if (role == 3) {
    scan_role2(bufPre, W_hh1, bufH, Mf, Bf, pr, pool);
  } else {
    fc_role2(bufH, fcW, fcb, outp, Bf, pr, pool);
  }
}

// ---------------------------------------------------------------------------
extern "C" void kernel_launch(void* const* d_in, const int* in_sizes, int n_in,
                              void* d_out, int out_size, void* d_ws, size_t ws_size,
                              hipStream_t stream) {
  const float* input = (const float*)d_in[0];
  const float* W_ih0 = (const float*)d_in[1];
  const float* W_hh0 = (const float*)d_in[2];
  const float* b_ih0 = (const float*)d_in[3];
  const float* b_hh0 = (const float*)d_in[4];
  const float* W_ih1 = (const float*)d_in[5];
  const float* W_hh1 = (const float*)d_in[6];
  const float* b_ih1 = (const float*)d_in[7];
  const float* b_hh1 = (const float*)d_in[8];
  const float* fc_W  = (const float*)d_in[9];
  const float* fc_b  = (const float*)d_in[10];
  float* out = (float*)d_out;

  // Workspace layout identical to verified R1/R4: 2 * M * H floats.
  float* bufPre = (float*)d_ws;               // pre1, later pre2 (in-place)
  float* bufH   = bufPre + (size_t)M * H;     // h1,   later h2   (in-place)

  zero_flags<<<1, 256, 0, stream>>>();
  pipeline<<<5 * NPAIR, 1024, 0, stream>>>(
      input, bufPre, bufH, W_ih0, b_ih0, b_hh0, W_hh0,
      W_ih1, b_ih1, b_hh1, W_hh1, fc_W, fc_b, out);
}

// Round 7
// 3219.791 us; speedup vs baseline: 1.7218x; 1.7218x over previous
//
#include <hip/hip_runtime.h>

// Problem constants (match reference)
constexpr int Bsz = 32;
constexpr int T   = 4096;
constexpr int P   = 64;
constexpr int IN  = 128;
constexpr int H   = 256;
constexpr long M  = (long)Bsz * T;   // 131072 rows
constexpr int FS  = 16;              // flag padding stride (ints, 64 B)
constexpr int C   = 16;              // pipeline chunk: rows per flag publish
constexpr int NC  = T / C;           // 256 chunks
constexpr int RW  = 320;             // padded 256-wide LDS row: 16 x (16+4)
constexpr int XW  = 192;             // padded 128-wide LDS row: 16 x (8+4)

using vf2 = __attribute__((ext_vector_type(2))) float;
using vf4 = __attribute__((ext_vector_type(4))) float;

// Progress flags (device-global; ws layout unchanged = 2*M*H floats).
// flag==v means "rows 0..v-1 of my output stream are globally visible".
// 4 producer roles (G,A,M,B) x 32 batches.
__device__ int g_flags[4 * Bsz * FS];

__global__ void zero_flags() {
  for (int i = threadIdx.x; i < 4 * Bsz * FS; i += 256) g_flags[i] = 0;
}

// ---------------------------------------------------------------------------
// Cross-WG primitives (agent scope = coherent across per-XCD L2s).
// ---------------------------------------------------------------------------
__device__ __forceinline__ vf2 gload2(const float* p) {
  unsigned long long v = __hip_atomic_load((const unsigned long long*)p,
      __ATOMIC_RELAXED, __HIP_MEMORY_SCOPE_AGENT);
  union { unsigned long long u; vf2 f; } c; c.u = v; return c.f;
}
__device__ __forceinline__ void gstore(float* p, float v) {
  __hip_atomic_store(p, v, __ATOMIC_RELAXED, __HIP_MEMORY_SCOPE_AGENT);
}
__device__ __forceinline__ void wait_ge(const int* f, int target, int& seen) {
  if (seen >= target) return;
  int v = __hip_atomic_load(const_cast<int*>(f), __ATOMIC_ACQUIRE,
                            __HIP_MEMORY_SCOPE_AGENT);
  while (v < target) {
    __builtin_amdgcn_s_sleep(8);
    v = __hip_atomic_load(const_cast<int*>(f), __ATOMIC_ACQUIRE,
                          __HIP_MEMORY_SCOPE_AGENT);
  }
  seen = v;
}
__device__ __forceinline__ void publish(int* f, int v) {
  __hip_atomic_store(f, v, __ATOMIC_RELEASE, __HIP_MEMORY_SCOPE_AGENT);
}

// Light barrier: LDS visibility only. Full barrier: drains vmcnt too (once
// per chunk, right before flag publish).
__device__ __forceinline__ void bar_lds() {
  asm volatile("s_waitcnt lgkmcnt(0)\n\ts_barrier" ::: "memory");
}
__device__ __forceinline__ void bar_full() {
  asm volatile("s_waitcnt vmcnt(0) lgkmcnt(0)\n\ts_barrier" ::: "memory");
}

__device__ __forceinline__ int padw(int c) { return (c >> 4) * 20 + (c & 15); }

// Packed 2xFP32 FMA/MUL (CDNA VOP3P, exact IEEE f32) — halves FMA issue count.
__device__ __forceinline__ void pkfma(vf2& d, vf2 a, vf2 b) {
  asm("v_pk_fma_f32 %0, %1, %2, %0" : "+v"(d) : "v"(a), "v"(b));
}
__device__ __forceinline__ vf2 pkmul(vf2 a, vf2 b) {
  vf2 d;
  asm("v_pk_mul_f32 %0, %1, %2" : "=v"(d) : "v"(a), "v"(b));
  return d;
}

// ds_swizzle pattern must be an integer-constant expression at the call site.
template <int PAT>
__device__ __forceinline__ float swz(float x) {
  return __int_as_float(__builtin_amdgcn_ds_swizzle(__float_as_int(x), PAT));
}

// Butterfly over the 16 ks-lanes (lane = jg(bits0-1) x ks(bits2-5)); on
// return lanes 0..15 hold the full dot for j = wv*16 + jg*4 + jj2.
__device__ __forceinline__ float reduce16(const float acc[4], int bit4, int bit8) {
  float t0 = bit4 ? acc[0] : acc[2];
  float t1 = bit4 ? acc[1] : acc[3];
  float r0 = swz<0x101F>(t0), r1 = swz<0x101F>(t1);
  float u0 = (bit4 ? acc[2] : acc[0]) + r0;
  float u1 = (bit4 ? acc[3] : acc[1]) + r1;
  float t2 = bit8 ? u0 : u1;
  float r2 = swz<0x201F>(t2);
  float s  = (bit8 ? u1 : u0) + r2;
  s += swz<0x401F>(s);
  s += __shfl_xor(s, 32, 64);
  return s;
}

__device__ __forceinline__ float tanh_f(float x) {
  float e = __expf(2.f * x);
  return 1.f - 2.f * __builtin_amdgcn_rcpf(e + 1.f);
}

// ---------------------------------------------------------------------------
// Packed matvec: (4 j x 16 k) per thread against a 256-wide padded LDS row.
// 4x ds_read_b128 + 4x(1 pk_mul + 7 pk_fma) + horizontal adds.
// ---------------------------------------------------------------------------
__device__ __forceinline__ float matvec_pk256(const vf2 w[4][8], const float* hb,
                                              int bit4, int bit8) {
  vf4 v0 = *(const vf4*)(hb + 0);
  vf4 v1 = *(const vf4*)(hb + 4);
  vf4 v2 = *(const vf4*)(hb + 8);
  vf4 v3 = *(const vf4*)(hb + 12);
  vf2 hh[8] = {v0.xy, v0.zw, v1.xy, v1.zw, v2.xy, v2.zw, v3.xy, v3.zw};
  float acc[4];
#pragma unroll
  for (int r = 0; r < 4; ++r) {
    vf2 a = pkmul(w[r][0], hh[0]);
#pragma unroll
    for (int q = 1; q < 8; ++q) pkfma(a, w[r][q], hh[q]);
    acc[r] = a.x + a.y;
  }
  __builtin_amdgcn_sched_barrier(0);
  return reduce16(acc, bit4, bit8);
}

__device__ __forceinline__ void load_w256(const float* Wm, int wv, int jg,
                                          int ks, vf2 w[4][8]) {
  const vf2* W2 = (const vf2*)Wm;
#pragma unroll
  for (int r = 0; r < 4; ++r)
#pragma unroll
    for (int q = 0; q < 8; ++q)
      w[r][q] = W2[(long)(wv * 16 + jg * 4 + r) * (H / 2) + ks * 8 + q];
#pragma unroll
  for (int r = 0; r < 4; ++r)
#pragma unroll
    for (int q = 0; q < 8; ++q)
      asm volatile("" : "+v"(w[r][q]));
}

// ---------------------------------------------------------------------------
// Role G: pre1[t] = W_ih0 @ x[t] + b_ih0 + b_hh0.  1 batch/WG, streaming.
// x staged in LDS as 16 slices of 8 floats padded to 12. Input is read-only
// => plain loads.
// ---------------------------------------------------------------------------
__device__ __forceinline__ void g_role(
    const float* __restrict__ xin, const float* __restrict__ Wih,
    const float* __restrict__ bi, const float* __restrict__ bh,
    float* pre1b, int* Gf, int b, float* pool) {
  const int tid = threadIdx.x, lane = tid & 63, wv = tid >> 6;
  const int jg = lane & 3, ks = lane >> 2;
  const int bit4 = lane & 4, bit8 = lane & 8;
  const int jj2 = ((lane >> 1) & 2) | ((lane >> 3) & 1);

  const vf2* W2 = (const vf2*)Wih;
  vf2 gw[4][4];
#pragma unroll
  for (int r = 0; r < 4; ++r)
#pragma unroll
    for (int q = 0; q < 4; ++q)
      gw[r][q] = W2[(long)(wv * 16 + jg * 4 + r) * (IN / 2) + ks * 4 + q];

  const int  jmine = wv * 16 + jg * 4 + jj2;
  const float bsum = bi[jmine] + bh[jmine];
  const long xb = (long)b * T * IN;
  float* o = pre1b + (long)b * T * H + jmine;
  // staging: chunk = 16 rows x 128 = 2048 floats = 1024 vf2, 1 per thread
  const int srow = tid >> 6, scol2 = tid & 63;
  const int so = srow * XW + (scol2 >> 2) * 12 + (scol2 & 3) * 2;
  float* xrp = pool;                         // [2][C][XW]

  *(vf2*)&xrp[so] = *(const vf2*)(xin + xb + 2 * tid);
  bar_lds();

#pragma unroll 1
  for (int k = 0; k < NC; ++k) {
    const int kn = k + 1;
    const bool more = (kn < NC);
    vf2 nx = {0.f, 0.f};
    if (more) nx = *(const vf2*)(xin + xb + (long)kn * C * IN + 2 * tid);
    const float* x0 = xrp + (k & 1) * C * XW;
#pragma unroll 2
    for (int r = 0; r < C; ++r) {
      const float* xa = x0 + r * XW + ks * 12;
      vf4 a0 = *(const vf4*)(xa);
      vf4 a1 = *(const vf4*)(xa + 4);
      vf2 hh[4] = {a0.xy, a0.zw, a1.xy, a1.zw};
      float acc[4];
#pragma unroll
      for (int r2 = 0; r2 < 4; ++r2) {
        vf2 a = pkmul(gw[r2][0], hh[0]);
        pkfma(a, gw[r2][1], hh[1]);
        pkfma(a, gw[r2][2], hh[2]);
        pkfma(a, gw[r2][3], hh[3]);
        acc[r2] = a.x + a.y;
      }
      float s = reduce16(acc, bit4, bit8) + bsum;
      if (lane < 16) gstore(o + (long)(k * C + r) * H, s);
    }
    if (more) *(vf2*)&xrp[(kn & 1) * C * XW + so] = nx;
    bar_full();                       // drain pre1 gstores before publish
    if (tid == 0) publish(Gf, kn * C);
  }
}

// ---------------------------------------------------------------------------
// Role A/B: recurrent scan, 1 batch/WG (chain latency is what matters — R6).
// Per step: ring p-read + pk-matvec + butterfly + tanh + LDS h write + LDS
// barrier. Per chunk: one flag wait, staged a chunk ahead via b64 atomics,
// one vmcnt drain + publish.
// ---------------------------------------------------------------------------
__device__ __forceinline__ void scan_role(
    const float* prebuf, const float* __restrict__ Wm, float* houtb,
    const int* inflag, int* outflag, int b, float* pool) {
  const int tid = threadIdx.x, lane = tid & 63, wv = tid >> 6;
  const int jg = lane & 3, ks = lane >> 2;
  const int bit4 = lane & 4, bit8 = lane & 8;
  const int jj2 = ((lane >> 1) & 2) | ((lane >> 3) & 1);

  vf2 wt[4][8]; load_w256(Wm, wv, jg, ks, wt);
  const int  jmine = wv * 16 + jg * 4 + jj2;
  const long base  = (long)b * T * H;
  float* ho = houtb + base + jmine;
  const int wr  = wv * 20 + (jg * 4 + jj2);
  const int prd = padw(jmine);
  // staging: chunk = 16 rows x 256 = 4096 floats = 2048 vf2; thread covers
  // vf2 indices tid and tid+1024.  row = i>>7, col2 = i&127.
  const int i0 = tid, i1 = tid + 1024;
  const int so0 = (i0 >> 7) * RW + ((i0 & 127) >> 3) * 20 + ((i0 & 127) & 7) * 2;
  const int so1 = (i1 >> 7) * RW + ((i1 & 127) >> 3) * 20 + ((i1 & 127) & 7) * 2;

  float* ringp = pool;                      // [2][C][RW]
  float* hdbp  = pool + 2 * C * RW;         // [2][RW]
  if (tid < 2 * RW) hdbp[tid] = 0.f;

  int seen = 0;
  wait_ge(inflag, C, seen);
  {
    vf2 a0 = gload2(prebuf + base + 2 * i0);
    vf2 a1 = gload2(prebuf + base + 2 * i1);
    *(vf2*)&ringp[so0] = a0;
    *(vf2*)&ringp[so1] = a1;
  }
  bar_full();

#pragma unroll 1
  for (int k = 0; k < NC; ++k) {
    const int kn = k + 1;
    const bool more = (kn < NC);
    vf2 s0 = {0.f, 0.f}, s1 = {0.f, 0.f};
    if (more) {
      wait_ge(inflag, (kn + 1) * C, seen);
      const float* nb = prebuf + base + (long)kn * C * H;
      s0 = gload2(nb + 2 * i0);
      s1 = gload2(nb + 2 * i1);
    }
    const float* rb = ringp + (k & 1) * C * RW;
#pragma unroll 2
    for (int r = 0; r < C; ++r) {           // t = k*C + r; k*C even
      float p = rb[r * RW + prd];
      float s = matvec_pk256(wt, hdbp + (r & 1) * RW + ks * 20, bit4, bit8);
      float hn = tanh_f(p + s);
      if (lane < 16) {
        hdbp[((r + 1) & 1) * RW + wr] = hn;
        gstore(ho + (long)(k * C + r) * H, hn);  // drained at chunk end
      }
      if (r != C - 1) bar_lds();
    }
    if (more) {
      float* wb = ringp + (kn & 1) * C * RW;
      *(vf2*)&wb[so0] = s0;
      *(vf2*)&wb[so1] = s1;
    }
    bar_full();                        // drain h gstores + ring ds_writes
    if (tid == 0) publish(outflag, kn * C);
  }
}

// ---------------------------------------------------------------------------
// Role M: pre2[t] = W_ih1 @ h1[t] + b_ih1 + b_hh1. Feed-forward stream, no
// per-step barrier.
// ---------------------------------------------------------------------------
__device__ __forceinline__ void mid_role(
    const float* h1b, const float* __restrict__ Wm,
    const float* __restrict__ bi, const float* __restrict__ bh,
    float* pre2b, const int* Af, int* Mf, int b, float* pool) {
  const int tid = threadIdx.x, lane = tid & 63, wv = tid >> 6;
  const int jg = lane & 3, ks = lane >> 2;
  const int bit4 = lane & 4, bit8 = lane & 8;
  const int jj2 = ((lane >> 1) & 2) | ((lane >> 3) & 1);

  vf2 wt[4][8]; load_w256(Wm, wv, jg, ks, wt);
  const int  jmine = wv * 16 + jg * 4 + jj2;
  const float bsum = bi[jmine] + bh[jmine];
  const long base  = (long)b * T * H;
  float* o = pre2b + base + jmine;
  const int i0 = tid, i1 = tid + 1024;
  const int so0 = (i0 >> 7) * RW + ((i0 & 127) >> 3) * 20 + ((i0 & 127) & 7) * 2;
  const int so1 = (i1 >> 7) * RW + ((i1 & 127) >> 3) * 20 + ((i1 & 127) & 7) * 2;
  float* ringp = pool;

  int seen = 0;
  wait_ge(Af, C, seen);
  {
    vf2 a0 = gload2(h1b + base + 2 * i0);
    vf2 a1 = gload2(h1b + base + 2 * i1);
    *(vf2*)&ringp[so0] = a0;
    *(vf2*)&ringp[so1] = a1;
  }
  bar_lds();

#pragma unroll 1
  for (int k = 0; k < NC; ++k) {
    const int kn = k + 1;
    const bool more = (kn < NC);
    vf2 s0 = {0.f, 0.f}, s1 = {0.f, 0.f};
    if (more) {
      wait_ge(Af, (kn + 1) * C, seen);
      const float* nb = h1b + base + (long)kn * C * H;
      s0 = gload2(nb + 2 * i0);
      s1 = gload2(nb + 2 * i1);
    }
    const float* rb = ringp + (k & 1) * C * RW;
#pragma unroll 2
    for (int r = 0; r < C; ++r) {
      float s = matvec_pk256(wt, rb + r * RW + ks * 20, bit4, bit8) + bsum;
      if (lane < 16) gstore(o + (long)(k * C + r) * H, s);
    }
    if (more) {
      float* wb = ringp + (kn & 1) * C * RW;
      *(vf2*)&wb[so0] = s0;
      *(vf2*)&wb[so1] = s1;
    }
    bar_full();                        // drain pre2 gstores before publish
    if (tid == 0) publish(Mf, kn * C);
  }
}

// ---------------------------------------------------------------------------
// Role F: out[t][p] = sigmoid(h2[t]·fcW[p] + fcb[p]). thread = (p = wv*4+jg)
// x (k-slice ks): 8 pk-MAC + full 16-lane fold.
// ---------------------------------------------------------------------------
__device__ __forceinline__ void fc_role(
    const float* h2b, const float* __restrict__ fcWm,
    const float* __restrict__ fcbv, float* __restrict__ outp,
    const int* Bf, int b, float* pool) {
  const int tid = threadIdx.x, lane = tid & 63, wv = tid >> 6;
  const int jg = lane & 3, ks = lane >> 2;
  const int p = wv * 4 + jg;

  const vf2* W2 = (const vf2*)fcWm;
  vf2 fw[8];
#pragma unroll
  for (int q = 0; q < 8; ++q) fw[q] = W2[(long)p * (H / 2) + ks * 8 + q];
  const float fb = fcbv[p];
  const long base  = (long)b * T * H;
  const long obase = (long)b * T * P;
  const int i0 = tid, i1 = tid + 1024;
  const int so0 = (i0 >> 7) * RW + ((i0 & 127) >> 3) * 20 + ((i0 & 127) & 7) * 2;
  const int so1 = (i1 >> 7) * RW + ((i1 & 127) >> 3) * 20 + ((i1 & 127) & 7) * 2;
  float* ringp = pool;

  int seen = 0;
  wait_ge(Bf, C, seen);
  {
    vf2 a0 = gload2(h2b + base + 2 * i0);
    vf2 a1 = gload2(h2b + base + 2 * i1);
    *(vf2*)&ringp[so0] = a0;
    *(vf2*)&ringp[so1] = a1;
  }
  bar_lds();

#pragma unroll 1
  for (int k = 0; k < NC; ++k) {
    const int kn = k + 1;
    const bool more = (kn < NC);
    vf2 s0 = {0.f, 0.f}, s1 = {0.f, 0.f};
    if (more) {
      wait_ge(Bf, (kn + 1) * C, seen);
      const float* nb = h2b + base + (long)kn * C * H;
      s0 = gload2(nb + 2 * i0);
      s1 = gload2(nb + 2 * i1);
    }
    const float* rb = ringp + (k & 1) * C * RW;
#pragma unroll 2
    for (int r = 0; r < C; ++r) {
      const float* hb = rb + r * RW + ks * 20;
      vf4 v0 = *(const vf4*)(hb + 0);
      vf4 v1 = *(const vf4*)(hb + 4);
      vf4 v2 = *(const vf4*)(hb + 8);
      vf4 v3 = *(const vf4*)(hb + 12);
      vf2 hh[8] = {v0.xy, v0.zw, v1.xy, v1.zw, v2.xy, v2.zw, v3.xy, v3.zw};
      vf2 a = pkmul(fw[0], hh[0]);
#pragma unroll
      for (int q = 1; q < 8; ++q) pkfma(a, fw[q], hh[q]);
      float s = a.x + a.y;
      s += swz<0x101F>(s); s += swz<0x201F>(s); s += swz<0x401F>(s);
      s += __shfl_xor(s, 32, 64);
      float sig = __builtin_amdgcn_rcpf(1.f + __expf(-(s + fb)));
      if (lane < 4) outp[obase + (long)(k * C + r) * P + wv * 4 + lane] = sig;
    }
    if (more) {
      float* wb = ringp + (kn & 1) * C * RW;
      *(vf2*)&wb[so0] = s0;
      *(vf2*)&wb[so1] = s1;
    }
    bar_lds();                          // ring visibility only (no publish)
  }
}

// ---------------------------------------------------------------------------
// 5-stage pipeline, 160 co-resident WGs (role = blk>>5, batch = blk&31):
//   G: input GEMM stream  x    -> pre1   (bufPre)
//   A: layer-1 scan       pre1 -> h1     (bufH)
//   M: W_ih1 stream       h1   -> pre2   (bufPre in-place; A staged pre1 rows
//                                         2 chunks before M writes them)
//   B: layer-2 scan       pre2 -> h2     (bufH in-place behind M's staging)
//   F: fc+sigmoid stream  h2   -> out
// Acyclic waits, full-depth buffers, 160 WGs x 16 waves all resident.
// ---------------------------------------------------------------------------
__global__ __attribute__((amdgpu_flat_work_group_size(1024, 1024),
                          amdgpu_waves_per_eu(4, 4)))
void pipeline(const float* __restrict__ input, float* bufPre, float* bufH,
              const float* __restrict__ W_ih0, const float* __restrict__ b_ih0,
              const float* __restrict__ b_hh0, const float* __restrict__ W_hh0,
              const float* __restrict__ W_ih1, const float* __restrict__ b_ih1,
              const float* __restrict__ b_hh1, const float* __restrict__ W_hh1,
              const float* __restrict__ fcW, const float* __restrict__ fcb,
              float* __restrict__ outp) {
  __shared__ float pool[2 * C * RW + 2 * RW];   // 43520 B
  const int blk = blockIdx.x, role = blk >> 5, b = blk & 31;
  int* Gf = g_flags + (0 * Bsz + b) * FS;
  int* Af = g_flags + (1 * Bsz + b) * FS;
  int* Mf = g_flags + (2 * Bsz + b) * FS;
  int* Bf = g_flags + (3 * Bsz + b) * FS;

  if (role == 0) {
    g_role(input, W_ih0, b_ih0, b_hh0, bufPre, Gf, b, pool);
  } else if (role == 1) {
    scan_role(bufPre, W_hh0, bufH, Gf, Af, b, pool);
  } else if (role == 2) {
    mid_role(bufH, W_ih1, b_ih1, b_hh1, bufPre, Af, Mf, b, pool);
  } else if (role == 3) {
    scan_role(bufPre, W_hh1, bufH, Mf, Bf, b, pool);
  } else {
    fc_role(bufH, fcW, fcb, outp, Bf, b, pool);
  }
}

// ---------------------------------------------------------------------------
extern "C" void kernel_launch(void* const* d_in, const int* in_sizes, int n_in,
                              void* d_out, int out_size, void* d_ws, size_t ws_size,
                              hipStream_t stream) {
  const float* input = (const float*)d_in[0];
  const float* W_ih0 = (const float*)d_in[1];
  const float* W_hh0 = (const float*)d_in[2];
  const float* b_ih0 = (const float*)d_in[3];
  const float* b_hh0 = (const float*)d_in[4];
  const float* W_ih1 = (const float*)d_in[5];
  const float* W_hh1 = (const float*)d_in[6];
  const float* b_ih1 = (const float*)d_in[7];
  const float* b_hh1 = (const float*)d_in[8];
  const float* fc_W  = (const float*)d_in[9];
  const float* fc_b  = (const float*)d_in[10];
  float* out = (float*)d_out;

  // Workspace layout identical to verified R1/R4: 2 * M * H floats.
  float* bufPre = (float*)d_ws;               // pre1, later pre2 (in-place)
  float* bufH   = bufPre + (size_t)M * H;     // h1,   later h2   (in-place)

  zero_flags<<<1, 256, 0, stream>>>();
  pipeline<<<5 * Bsz, 1024, 0, stream>>>(
      input, bufPre, bufH, W_ih0, b_ih0, b_hh0, W_hh0,
      W_ih1, b_ih1, b_hh1, W_hh1, fc_W, fc_b, out);
}

// Round 8
// 3026.320 us; speedup vs baseline: 1.8318x; 1.0639x over previous
//
#include <hip/hip_runtime.h>

// Problem constants (match reference)
constexpr int Bsz = 32;
constexpr int T   = 4096;
constexpr int P   = 64;
constexpr int IN  = 128;
constexpr int H   = 256;
constexpr long M  = (long)Bsz * T;   // 131072 rows
constexpr int FS  = 16;              // flag padding stride (ints, 64 B)
constexpr int C   = 16;              // pipeline chunk: rows per flag publish
constexpr int NC  = T / C;           // 256 chunks
constexpr int RW  = 320;             // padded 256-wide LDS row: 16 x (16+4)
constexpr int XW  = 192;             // padded 128-wide LDS row: 16 x (8+4)

using vf2 = __attribute__((ext_vector_type(2))) float;
using vf4 = __attribute__((ext_vector_type(4))) float;

// Progress flags (device-global; ws layout unchanged = 2*M*H floats).
// flag==v means "rows 0..v-1 of my output stream are globally visible".
__device__ int g_flags[4 * Bsz * FS];

__global__ void zero_flags() {
  for (int i = threadIdx.x; i < 4 * Bsz * FS; i += 256) g_flags[i] = 0;
}

// ---------------------------------------------------------------------------
// Cross-WG primitives (agent scope = coherent across per-XCD L2s).
// ---------------------------------------------------------------------------
__device__ __forceinline__ vf2 gload2(const float* p) {
  unsigned long long v = __hip_atomic_load((const unsigned long long*)p,
      __ATOMIC_RELAXED, __HIP_MEMORY_SCOPE_AGENT);
  union { unsigned long long u; vf2 f; } c; c.u = v; return c.f;
}
__device__ __forceinline__ void gstore(float* p, float v) {
  __hip_atomic_store(p, v, __ATOMIC_RELAXED, __HIP_MEMORY_SCOPE_AGENT);
}
__device__ __forceinline__ void wait_ge(const int* f, int target, int& seen) {
  if (seen >= target) return;
  int v = __hip_atomic_load(const_cast<int*>(f), __ATOMIC_ACQUIRE,
                            __HIP_MEMORY_SCOPE_AGENT);
  while (v < target) {
    __builtin_amdgcn_s_sleep(8);
    v = __hip_atomic_load(const_cast<int*>(f), __ATOMIC_ACQUIRE,
                          __HIP_MEMORY_SCOPE_AGENT);
  }
  seen = v;
}
__device__ __forceinline__ void publish(int* f, int v) {
  __hip_atomic_store(f, v, __ATOMIC_RELEASE, __HIP_MEMORY_SCOPE_AGENT);
}

// Light barrier: LDS visibility only. Full barrier: drains vmcnt too (once
// per chunk, right before flag publish).
__device__ __forceinline__ void bar_lds() {
  asm volatile("s_waitcnt lgkmcnt(0)\n\ts_barrier" ::: "memory");
}
__device__ __forceinline__ void bar_full() {
  asm volatile("s_waitcnt vmcnt(0) lgkmcnt(0)\n\ts_barrier" ::: "memory");
}

__device__ __forceinline__ int padw(int c) { return (c >> 4) * 20 + (c & 15); }

// Packed 2xFP32 FMA/MUL (CDNA VOP3P, exact IEEE f32).
__device__ __forceinline__ void pkfma(vf2& d, vf2 a, vf2 b) {
  asm("v_pk_fma_f32 %0, %1, %2, %0" : "+v"(d) : "v"(a), "v"(b));
}
__device__ __forceinline__ vf2 pkmul(vf2 a, vf2 b) {
  vf2 d;
  asm("v_pk_mul_f32 %0, %1, %2" : "=v"(d) : "v"(a), "v"(b));
  return d;
}

// ---------------------------------------------------------------------------
// VALU lane-reduction (replaces the DS-pipe swizzle butterfly: 4 serial DS
// ops @~120cy each -> ~8 VALU ops @~8cy).
//  - bits 2-3 (within 16-lane DPP row): rotate-accumulate (row_ror 4, 8).
//  - bits 4-5: v_permlane16/32_swap SELF-swap (mov copy + swap + add).
//    Self-swap+add is semantics-robust: whichever row pairing the swap uses,
//    summing the two copies yields the xor-partner fold. "=&v" early-clobber
//    guarantees distinct registers; s_nop 1 guards the VALU->permlane hazard.
// ---------------------------------------------------------------------------
template <int CTRL>
__device__ __forceinline__ float dppadd(float x) {
  int r = __builtin_amdgcn_update_dpp(0, __float_as_int(x), CTRL, 0xF, 0xF, false);
  return x + __int_as_float(r);
}
__device__ __forceinline__ float fold16self(float x) {
  float y;
  asm volatile("v_mov_b32 %1, %0\n\ts_nop 1\n\tv_permlane16_swap_b32 %0, %1"
               : "+v"(x), "=&v"(y));
  return x + y;
}
__device__ __forceinline__ float fold32self(float x) {
  float y;
  asm volatile("v_mov_b32 %1, %0\n\ts_nop 1\n\tv_permlane32_swap_b32 %0, %1"
               : "+v"(x), "=&v"(y));
  return x + y;
}

// acc[q] = partial dot of row j = base + (lane&3)*4 + q over this lane's
// 16-float k-slice (ks = lane>>2). After bits2-3 DPP fold, every lane holds
// acc_q folded over ks bits 0-1; lane bits 2-3 are invariant under the
// remaining xor16/xor32 folds, so we SELECT acc[(lane>>2)&3] first (3
// cndmask), then fold bits 4-5 on the single value. Writer lanes (<16) end
// with the full dot for j = wv*16 + (lane&3)*4 + ((lane>>2)&3).
__device__ __forceinline__ float fold_jsel(const float acc[4], int lane) {
  float a0 = dppadd<0x128>(dppadd<0x124>(acc[0]));
  float a1 = dppadd<0x128>(dppadd<0x124>(acc[1]));
  float a2 = dppadd<0x128>(dppadd<0x124>(acc[2]));
  float a3 = dppadd<0x128>(dppadd<0x124>(acc[3]));
  float v01 = (lane & 4) ? a1 : a0;
  float v23 = (lane & 4) ? a3 : a2;
  float v   = (lane & 8) ? v23 : v01;
  return fold32self(fold16self(v));
}
// Single-acc variant (role F): full fold over lane bits 2-5, all lanes.
__device__ __forceinline__ float fold_all(float s) {
  s = dppadd<0x124>(s);
  s = dppadd<0x128>(s);
  return fold32self(fold16self(s));
}

__device__ __forceinline__ float tanh_f(float x) {
  float e = __expf(2.f * x);
  return 1.f - 2.f * __builtin_amdgcn_rcpf(e + 1.f);
}

// ---------------------------------------------------------------------------
// Packed matvec: (4 j x 16 k) per thread against a 256-wide padded LDS row.
// ---------------------------------------------------------------------------
__device__ __forceinline__ float matvec_pk256(const vf2 w[4][8], const float* hb,
                                              int lane) {
  vf4 v0 = *(const vf4*)(hb + 0);
  vf4 v1 = *(const vf4*)(hb + 4);
  vf4 v2 = *(const vf4*)(hb + 8);
  vf4 v3 = *(const vf4*)(hb + 12);
  vf2 hh[8] = {v0.xy, v0.zw, v1.xy, v1.zw, v2.xy, v2.zw, v3.xy, v3.zw};
  float acc[4];
#pragma unroll
  for (int r = 0; r < 4; ++r) {
    vf2 a = pkmul(w[r][0], hh[0]);
#pragma unroll
    for (int q = 1; q < 8; ++q) pkfma(a, w[r][q], hh[q]);
    acc[r] = a.x + a.y;
  }
  __builtin_amdgcn_sched_barrier(0);
  return fold_jsel(acc, lane);
}

__device__ __forceinline__ void load_w256(const float* Wm, int wv, int jg,
                                          int ks, vf2 w[4][8]) {
  const vf2* W2 = (const vf2*)Wm;
#pragma unroll
  for (int r = 0; r < 4; ++r)
#pragma unroll
    for (int q = 0; q < 8; ++q)
      w[r][q] = W2[(long)(wv * 16 + jg * 4 + r) * (H / 2) + ks * 8 + q];
#pragma unroll
  for (int r = 0; r < 4; ++r)
#pragma unroll
    for (int q = 0; q < 8; ++q)
      asm volatile("" : "+v"(w[r][q]));
}

// ---------------------------------------------------------------------------
// Role G: pre1[t] = W_ih0 @ x[t] + b_ih0 + b_hh0.  1 batch/WG, streaming.
// ---------------------------------------------------------------------------
__device__ __forceinline__ void g_role(
    const float* __restrict__ xin, const float* __restrict__ Wih,
    const float* __restrict__ bi, const float* __restrict__ bh,
    float* pre1b, int* Gf, int b, float* pool) {
  const int tid = threadIdx.x, lane = tid & 63, wv = tid >> 6;
  const int jg = lane & 3, ks = lane >> 2;

  const vf2* W2 = (const vf2*)Wih;
  vf2 gw[4][4];
#pragma unroll
  for (int r = 0; r < 4; ++r)
#pragma unroll
    for (int q = 0; q < 4; ++q)
      gw[r][q] = W2[(long)(wv * 16 + jg * 4 + r) * (IN / 2) + ks * 4 + q];

  const int  jmine = wv * 16 + jg * 4 + (ks & 3);
  const float bsum = bi[jmine] + bh[jmine];
  const long xb = (long)b * T * IN;
  float* o = pre1b + (long)b * T * H + jmine;
  const int srow = tid >> 6, scol2 = tid & 63;
  const int so = srow * XW + (scol2 >> 2) * 12 + (scol2 & 3) * 2;
  float* xrp = pool;                         // [2][C][XW]

  *(vf2*)&xrp[so] = *(const vf2*)(xin + xb + 2 * tid);
  bar_lds();

#pragma unroll 1
  for (int k = 0; k < NC; ++k) {
    const int kn = k + 1;
    const bool more = (kn < NC);
    vf2 nx = {0.f, 0.f};
    if (more) nx = *(const vf2*)(xin + xb + (long)kn * C * IN + 2 * tid);
    const float* x0 = xrp + (k & 1) * C * XW;
#pragma unroll 2
    for (int r = 0; r < C; ++r) {
      const float* xa = x0 + r * XW + ks * 12;
      vf4 a0 = *(const vf4*)(xa);
      vf4 a1 = *(const vf4*)(xa + 4);
      vf2 hh[4] = {a0.xy, a0.zw, a1.xy, a1.zw};
      float acc[4];
#pragma unroll
      for (int r2 = 0; r2 < 4; ++r2) {
        vf2 a = pkmul(gw[r2][0], hh[0]);
        pkfma(a, gw[r2][1], hh[1]);
        pkfma(a, gw[r2][2], hh[2]);
        pkfma(a, gw[r2][3], hh[3]);
        acc[r2] = a.x + a.y;
      }
      float s = fold_jsel(acc, lane) + bsum;
      if (lane < 16) gstore(o + (long)(k * C + r) * H, s);
    }
    if (more) *(vf2*)&xrp[(kn & 1) * C * XW + so] = nx;
    bar_full();                       // drain pre1 gstores before publish
    if (tid == 0) publish(Gf, kn * C);
  }
}

// ---------------------------------------------------------------------------
// Role A/B: recurrent scan, 1 batch/WG. Per step: ring p-read + pk-matvec +
// VALU fold + tanh + LDS h write + LDS barrier. Per chunk: one flag wait
// (staged a chunk ahead), one vmcnt drain + publish.
// ---------------------------------------------------------------------------
__device__ __forceinline__ void scan_role(
    const float* prebuf, const float* __restrict__ Wm, float* houtb,
    const int* inflag, int* outflag, int b, float* pool) {
  const int tid = threadIdx.x, lane = tid & 63, wv = tid >> 6;
  const int jg = lane & 3, ks = lane >> 2;

  vf2 wt[4][8]; load_w256(Wm, wv, jg, ks, wt);
  const int  jmine = wv * 16 + jg * 4 + (ks & 3);
  const long base  = (long)b * T * H;
  float* ho = houtb + base + jmine;
  const int wr  = wv * 20 + (jg * 4 + (ks & 3));
  const int prd = padw(jmine);
  const int i0 = tid, i1 = tid + 1024;
  const int so0 = (i0 >> 7) * RW + ((i0 & 127) >> 3) * 20 + ((i0 & 127) & 7) * 2;
  const int so1 = (i1 >> 7) * RW + ((i1 & 127) >> 3) * 20 + ((i1 & 127) & 7) * 2;

  float* ringp = pool;                      // [2][C][RW]
  float* hdbp  = pool + 2 * C * RW;         // [2][RW]
  if (tid < 2 * RW) hdbp[tid] = 0.f;

  int seen = 0;
  wait_ge(inflag, C, seen);
  {
    vf2 a0 = gload2(prebuf + base + 2 * i0);
    vf2 a1 = gload2(prebuf + base + 2 * i1);
    *(vf2*)&ringp[so0] = a0;
    *(vf2*)&ringp[so1] = a1;
  }
  bar_full();

#pragma unroll 1
  for (int k = 0; k < NC; ++k) {
    const int kn = k + 1;
    const bool more = (kn < NC);
    vf2 s0 = {0.f, 0.f}, s1 = {0.f, 0.f};
    if (more) {
      wait_ge(inflag, (kn + 1) * C, seen);
      const float* nb = prebuf + base + (long)kn * C * H;
      s0 = gload2(nb + 2 * i0);
      s1 = gload2(nb + 2 * i1);
    }
    const float* rb = ringp + (k & 1) * C * RW;
#pragma unroll 2
    for (int r = 0; r < C; ++r) {           // t = k*C + r; k*C even
      float p = rb[r * RW + prd];
      float s = matvec_pk256(wt, hdbp + (r & 1) * RW + ks * 20, lane);
      float hn = tanh_f(p + s);
      if (lane < 16) {
        hdbp[((r + 1) & 1) * RW + wr] = hn;
        gstore(ho + (long)(k * C + r) * H, hn);  // drained at chunk end
      }
      if (r != C - 1) bar_lds();
    }
    if (more) {
      float* wb = ringp + (kn & 1) * C * RW;
      *(vf2*)&wb[so0] = s0;
      *(vf2*)&wb[so1] = s1;
    }
    bar_full();                        // drain h gstores + ring ds_writes
    if (tid == 0) publish(outflag, kn * C);
  }
}

// ---------------------------------------------------------------------------
// Role M: pre2[t] = W_ih1 @ h1[t] + b_ih1 + b_hh1. Feed-forward stream.
// ---------------------------------------------------------------------------
__device__ __forceinline__ void mid_role(
    const float* h1b, const float* __restrict__ Wm,
    const float* __restrict__ bi, const float* __restrict__ bh,
    float* pre2b, const int* Af, int* Mf, int b, float* pool) {
  const int tid = threadIdx.x, lane = tid & 63, wv = tid >> 6;
  const int jg = lane & 3, ks = lane >> 2;

  vf2 wt[4][8]; load_w256(Wm, wv, jg, ks, wt);
  const int  jmine = wv * 16 + jg * 4 + (ks & 3);
  const float bsum = bi[jmine] + bh[jmine];
  const long base  = (long)b * T * H;
  float* o = pre2b + base + jmine;
  const int i0 = tid, i1 = tid + 1024;
  const int so0 = (i0 >> 7) * RW + ((i0 & 127) >> 3) * 20 + ((i0 & 127) & 7) * 2;
  const int so1 = (i1 >> 7) * RW + ((i1 & 127) >> 3) * 20 + ((i1 & 127) & 7) * 2;
  float* ringp = pool;

  int seen = 0;
  wait_ge(Af, C, seen);
  {
    vf2 a0 = gload2(h1b + base + 2 * i0);
    vf2 a1 = gload2(h1b + base + 2 * i1);
    *(vf2*)&ringp[so0] = a0;
    *(vf2*)&ringp[so1] = a1;
  }
  bar_lds();

#pragma unroll 1
  for (int k = 0; k < NC; ++k) {
    const int kn = k + 1;
    const bool more = (kn < NC);
    vf2 s0 = {0.f, 0.f}, s1 = {0.f, 0.f};
    if (more) {
      wait_ge(Af, (kn + 1) * C, seen);
      const float* nb = h1b + base + (long)kn * C * H;
      s0 = gload2(nb + 2 * i0);
      s1 = gload2(nb + 2 * i1);
    }
    const float* rb = ringp + (k & 1) * C * RW;
#pragma unroll 2
    for (int r = 0; r < C; ++r) {
      float s = matvec_pk256(wt, rb + r * RW + ks * 20, lane) + bsum;
      if (lane < 16) gstore(o + (long)(k * C + r) * H, s);
    }
    if (more) {
      float* wb = ringp + (kn & 1) * C * RW;
      *(vf2*)&wb[so0] = s0;
      *(vf2*)&wb[so1] = s1;
    }
    bar_full();                        // drain pre2 gstores before publish
    if (tid == 0) publish(Mf, kn * C);
  }
}

// ---------------------------------------------------------------------------
// Role F: out[t][p] = sigmoid(h2[t]·fcW[p] + fcb[p]).
// ---------------------------------------------------------------------------
__device__ __forceinline__ void fc_role(
    const float* h2b, const float* __restrict__ fcWm,
    const float* __restrict__ fcbv, float* __restrict__ outp,
    const int* Bf, int b, float* pool) {
  const int tid = threadIdx.x, lane = tid & 63, wv = tid >> 6;
  const int jg = lane & 3, ks = lane >> 2;
  const int p = wv * 4 + jg;

  const vf2* W2 = (const vf2*)fcWm;
  vf2 fw[8];
#pragma unroll
  for (int q = 0; q < 8; ++q) fw[q] = W2[(long)p * (H / 2) + ks * 8 + q];
  const float fb = fcbv[p];
  const long base  = (long)b * T * H;
  const long obase = (long)b * T * P;
  const int i0 = tid, i1 = tid + 1024;
  const int so0 = (i0 >> 7) * RW + ((i0 & 127) >> 3) * 20 + ((i0 & 127) & 7) * 2;
  const int so1 = (i1 >> 7) * RW + ((i1 & 127) >> 3) * 20 + ((i1 & 127) & 7) * 2;
  float* ringp = pool;

  int seen = 0;
  wait_ge(Bf, C, seen);
  {
    vf2 a0 = gload2(h2b + base + 2 * i0);
    vf2 a1 = gload2(h2b + base + 2 * i1);
    *(vf2*)&ringp[so0] = a0;
    *(vf2*)&ringp[so1] = a1;
  }
  bar_lds();

#pragma unroll 1
  for (int k = 0; k < NC; ++k) {
    const int kn = k + 1;
    const bool more = (kn < NC);
    vf2 s0 = {0.f, 0.f}, s1 = {0.f, 0.f};
    if (more) {
      wait_ge(Bf, (kn + 1) * C, seen);
      const float* nb = h2b + base + (long)kn * C * H;
      s0 = gload2(nb + 2 * i0);
      s1 = gload2(nb + 2 * i1);
    }
    const float* rb = ringp + (k & 1) * C * RW;
#pragma unroll 2
    for (int r = 0; r < C; ++r) {
      const float* hb = rb + r * RW + ks * 20;
      vf4 v0 = *(const vf4*)(hb + 0);
      vf4 v1 = *(const vf4*)(hb + 4);
      vf4 v2 = *(const vf4*)(hb + 8);
      vf4 v3 = *(const vf4*)(hb + 12);
      vf2 hh[8] = {v0.xy, v0.zw, v1.xy, v1.zw, v2.xy, v2.zw, v3.xy, v3.zw};
      vf2 a = pkmul(fw[0], hh[0]);
#pragma unroll
      for (int q = 1; q < 8; ++q) pkfma(a, fw[q], hh[q]);
      float s = fold_all(a.x + a.y);
      float sig = __builtin_amdgcn_rcpf(1.f + __expf(-(s + fb)));
      if (lane < 4) outp[obase + (long)(k * C + r) * P + wv * 4 + lane] = sig;
    }
    if (more) {
      float* wb = ringp + (kn & 1) * C * RW;
      *(vf2*)&wb[so0] = s0;
      *(vf2*)&wb[so1] = s1;
    }
    bar_lds();                          // ring visibility only (no publish)
  }
}

// ---------------------------------------------------------------------------
// 5-stage pipeline, 160 co-resident WGs (role = blk>>5, batch = blk&31):
//   G: input GEMM stream  x    -> pre1   (bufPre)
//   A: layer-1 scan       pre1 -> h1     (bufH)
//   M: W_ih1 stream       h1   -> pre2   (bufPre in-place, 2 chunks behind)
//   B: layer-2 scan       pre2 -> h2     (bufH in-place, 2 chunks behind)
//   F: fc+sigmoid stream  h2   -> out
// ---------------------------------------------------------------------------
__global__ __attribute__((amdgpu_flat_work_group_size(1024, 1024),
                          amdgpu_waves_per_eu(4, 4)))
void pipeline(const float* __restrict__ input, float* bufPre, float* bufH,
              const float* __restrict__ W_ih0, const float* __restrict__ b_ih0,
              const float* __restrict__ b_hh0, const float* __restrict__ W_hh0,
              const float* __restrict__ W_ih1, const float* __restrict__ b_ih1,
              const float* __restrict__ b_hh1, const float* __restrict__ W_hh1,
              const float* __restrict__ fcW, const float* __restrict__ fcb,
              float* __restrict__ outp) {
  __shared__ float pool[2 * C * RW + 2 * RW];   // 43520 B
  const int blk = blockIdx.x, role = blk >> 5, b = blk & 31;
  int* Gf = g_flags + (0 * Bsz + b) * FS;
  int* Af = g_flags + (1 * Bsz + b) * FS;
  int* Mf = g_flags + (2 * Bsz + b) * FS;
  int* Bf = g_flags + (3 * Bsz + b) * FS;

  if (role == 0) {
    g_role(input, W_ih0, b_ih0, b_hh0, bufPre, Gf, b, pool);
  } else if (role == 1) {
    scan_role(bufPre, W_hh0, bufH, Gf, Af, b, pool);
  } else if (role == 2) {
    mid_role(bufH, W_ih1, b_ih1, b_hh1, bufPre, Af, Mf, b, pool);
  } else if (role == 3) {
    scan_role(bufPre, W_hh1, bufH, Mf, Bf, b, pool);
  } else {
    fc_role(bufH, fcW, fcb, outp, Bf, b, pool);
  }
}

// ---------------------------------------------------------------------------
extern "C" void kernel_launch(void* const* d_in, const int* in_sizes, int n_in,
                              void* d_out, int out_size, void* d_ws, size_t ws_size,
                              hipStream_t stream) {
  const float* input = (const float*)d_in[0];
  const float* W_ih0 = (const float*)d_in[1];
  const float* W_hh0 = (const float*)d_in[2];
  const float* b_ih0 = (const float*)d_in[3];
  const float* b_hh0 = (const float*)d_in[4];
  const float* W_ih1 = (const float*)d_in[5];
  const float* W_hh1 = (const float*)d_in[6];
  const float* b_ih1 = (const float*)d_in[7];
  const float* b_hh1 = (const float*)d_in[8];
  const float* fc_W  = (const float*)d_in[9];
  const float* fc_b  = (const float*)d_in[10];
  float* out = (float*)d_out;

  // Workspace layout identical to verified R1/R4/R7: 2 * M * H floats.
  float* bufPre = (float*)d_ws;               // pre1, later pre2 (in-place)
  float* bufH   = bufPre + (size_t)M * H;     // h1,   later h2   (in-place)

  zero_flags<<<1, 256, 0, stream>>>();
  pipeline<<<5 * Bsz, 1024, 0, stream>>>(
      input, bufPre, bufH, W_ih0, b_ih0, b_hh0, W_hh0,
      W_ih1, b_ih1, b_hh1, W_hh1, fc_W, fc_b, out);
}